// Round 11
// baseline (86.551 us; speedup 1.0000x reference)
//
#include <hip/hip_runtime.h>
#include <hip/hip_bf16.h>

// Problem-fixed shapes: features [4,64,2048] fp32 (feats[m][c] = flat[c*8192+m]),
// labels [8192] int32, NUM_CLASSES=4, TEMP=0.07, scalar fp32 out.
#define M_TOT 8192
#define NCLS 4
#define NSEL_CAP 4096   // nsel ~ 3000 (deterministic for this fixed input); 4096 guard
#define NT 64           // 64x64 tile grid covers NSEL_CAP

typedef __attribute__((ext_vector_type(8)))  short short8v;  // 8 bf16 = 4 VGPRs
typedef __attribute__((ext_vector_type(16))) float f32x16;   // MFMA 32x32 acc

// async 16B global->LDS copy (device pass only: host pass must not see the
// builtin, its pointer params fail host typechecking)
__device__ __forceinline__ void async_copy16(const void* gsrc, void* ldst) {
#if defined(__HIP_DEVICE_COMPILE__)
    __builtin_amdgcn_global_load_lds(
        (const __attribute__((address_space(1))) void*)gsrc,
        (__attribute__((address_space(3))) void*)ldst, 16, 0, 0);
#endif
}

// ---------------- JAX threefry-2x32, key = PRNGKey(42) = (0, 42) -------------
// Counter pair (j, j+4096); JAX output: bits[m] = x0 if m<4096 else x1.
__device__ __forceinline__ unsigned int rotl32(unsigned int x, unsigned int r) {
    return (x << r) | (x >> (32u - r));
}

__device__ __forceinline__ uint2 threefry_pair_key42(unsigned int j) {
    const unsigned int ks0 = 0u;
    const unsigned int ks1 = 42u;
    const unsigned int ks2 = 0x1BD11BDAu ^ 0u ^ 42u;
    unsigned int x0 = j + ks0;
    unsigned int x1 = (j + 4096u) + ks1;
#define TF_RND(r) { x0 += x1; x1 = rotl32(x1, (r)); x1 ^= x0; }
    TF_RND(13u) TF_RND(15u) TF_RND(26u) TF_RND(6u)
    x0 += ks1; x1 += ks2 + 1u;
    TF_RND(17u) TF_RND(29u) TF_RND(16u) TF_RND(24u)
    x0 += ks2; x1 += ks0 + 2u;
    TF_RND(13u) TF_RND(15u) TF_RND(26u) TF_RND(6u)
    x0 += ks0; x1 += ks1 + 3u;
    TF_RND(17u) TF_RND(29u) TF_RND(16u) TF_RND(24u)
    x0 += ks1; x1 += ks2 + 4u;
    TF_RND(13u) TF_RND(15u) TF_RND(26u) TF_RND(6u)
    x0 += ks2; x1 += ks0 + 5u;
#undef TF_RND
    return make_uint2(x0, x1);
}

// JAX uniform from bits: bitcast((bits>>9)|0x3F800000) - 1.0; select iff u < p.
__device__ __forceinline__ float bits_to_unit(unsigned int bits) {
    return __uint_as_float((bits >> 9) | 0x3F800000u) - 1.0f;
}

// bf16 round-to-nearest-even helpers
__device__ __forceinline__ unsigned short f2bf(float x) {
    const unsigned int u = __float_as_uint(x);
    return (unsigned short)((u + 0x7FFFu + ((u >> 16) & 1u)) >> 16);
}
__device__ __forceinline__ float bf2f(unsigned short b) {
    return __uint_as_float(((unsigned int)b) << 16);
}

// Global nv layout is FRAGMENT-MAJOR, identical to pair's LDS layout:
//   nv[plane(hi=0,lo=1)][chunk c 0..7][point 0..4095][8 bf16]
#define NV_OFS(plane, c, p) (((((plane) << 3) + (c)) << 12) + (p))

// ---------------- kernel 1: fused select + normalize (coalesced reads) -------
// 128 blocks x 256. Every block redundantly computes the full selection
// (pure function of labels + threefry). Block b then normalizes the selected
// points whose index m lies in [64b, 64b+64): slot mapping recorded in LDS
// during compaction; features staged through a padded LDS tile with
// fully-coalesced float4 global reads (fixes the 16x line amplification of
// the old 32KB-strided gather).
__global__ __launch_bounds__(256) void select_norm_kernel(
        const float* __restrict__ features,
        const int* __restrict__ labels,
        int* __restrict__ nsel_g,
        int* __restrict__ lab_sel,
        unsigned short* __restrict__ nv,     // [2][8][4096][8] bf16
        float* __restrict__ pos,
        float* __restrict__ neg) {
    __shared__ int   hist[NCLS];
    __shared__ float keepp[NCLS];
    __shared__ int   wtot[4];
    __shared__ int   slot_local[64];         // m&63 -> global slot (or -1)
    __shared__ float tile[64][65];           // [c][m local], +1 pad
    const int t = threadIdx.x, b = blockIdx.x;
    const int lane = t & 63, w = t >> 6;

    const int gid = b * 256 + t;
    if (gid < NSEL_CAP) { pos[gid] = 0.0f; neg[gid] = 0.0f; }
    if (t < NCLS) hist[t] = 0;
    if (t < 64) slot_local[t] = -1;
    __syncthreads();

    // full histogram (redundant per block; L2-cached labels)
    {
        const int m0 = t * 32;
        int c0 = 0, c1 = 0, c2 = 0, c3 = 0;
        for (int r = 0; r < 32; ++r) {
            const int lab = labels[m0 + r];
            c0 += (lab == 0); c1 += (lab == 1); c2 += (lab == 2); c3 += (lab == 3);
        }
        int cc[4] = {c0, c1, c2, c3};
        #pragma unroll
        for (int cls = 0; cls < NCLS; ++cls) {
            int v = cc[cls];
            for (int off = 32; off > 0; off >>= 1) v += __shfl_down(v, off, 64);
            if (lane == 0) atomicAdd(&hist[cls], v);
        }
    }
    __syncthreads();
    if (t < NCLS) keepp[t] = fminf(750.0f / ((float)hist[t] + 1.0f), 1.0f);
    __syncthreads();

    // selection: thread t owns counter-lanes j = t*16..t*16+15, each yielding
    // m=j (x0) and m=j+4096 (x1).
    const int jb = t * 16;
    unsigned int flags = 0u;
    int cnt = 0;
    for (int r = 0; r < 16; ++r) {
        const uint2 bb = threefry_pair_key42((unsigned int)(jb + r));
        if (bits_to_unit(bb.x) < keepp[labels[jb + r]])        { flags |= 1u << r;        ++cnt; }
        if (bits_to_unit(bb.y) < keepp[labels[jb + r + 4096]]) { flags |= 1u << (16 + r); ++cnt; }
    }
    // wave-inclusive scan -> block-wide exclusive base
    int x = cnt;
    #pragma unroll
    for (int off = 1; off < 64; off <<= 1) {
        const int y = __shfl_up(x, off, 64);
        if (lane >= off) x += y;
    }
    if (lane == 63) wtot[w] = x;
    const int excl = x - cnt;
    __syncthreads();
    int base = excl;
    for (int w2 = 0; w2 < w; ++w2) base += wtot[w2];
    const int nsel = wtot[0] + wtot[1] + wtot[2] + wtot[3];
    if (b == 0 && t == 0) *nsel_g = nsel;
    // compaction: write lab_sel[slot] globally; record slots for own m-range
    for (int r = 0; r < 16; ++r) {
        if (flags & (1u << r)) {
            const int m = jb + r;
            lab_sel[base] = labels[m];
            if ((m >> 6) == b) slot_local[m & 63] = base;
            ++base;
        }
        if (flags & (1u << (16 + r))) {
            const int m = jb + r + 4096;
            lab_sel[base] = labels[m];
            if ((m >> 6) == b) slot_local[m & 63] = base;
            ++base;
        }
    }

    // stage this block's 64-point feature slab, fully coalesced:
    // 1024 float4 slots: c = idx>>4, mg4 = (idx&15)*4
    #pragma unroll
    for (int it4 = 0; it4 < 4; ++it4) {
        const int idx = it4 * 256 + t;
        const int c   = idx >> 4;
        const int mg4 = (idx & 15) * 4;
        const float4 v = *(const float4*)&features[c * M_TOT + b * 64 + mg4];
        tile[c][mg4]     = v.x;
        tile[c][mg4 + 1] = v.y;
        tile[c][mg4 + 2] = v.z;
        tile[c][mg4 + 3] = v.w;
    }
    __syncthreads();

    // normalize: 8 threads/point from the LDS tile, 2 passes of 32 points
    const int kg = t & 7;
    #pragma unroll
    for (int pass = 0; pass < 2; ++pass) {
        const int mm = pass * 32 + (t >> 3);
        const int slot = slot_local[mm];
        float v[8];
        float ss = 0.0f;
        #pragma unroll
        for (int q = 0; q < 8; ++q) {
            v[q] = tile[kg * 8 + q][mm];
            ss += v[q] * v[q];
        }
        ss += __shfl_xor(ss, 1, 8);
        ss += __shfl_xor(ss, 2, 8);
        ss += __shfl_xor(ss, 4, 8);
        if (slot < 0) continue;
        const float rn = rsqrtf(ss);
        unsigned short hs[8], ls[8];
        #pragma unroll
        for (int q = 0; q < 8; ++q) {
            const float xx = v[q] * rn;
            const unsigned short h = f2bf(xx);
            hs[q] = h;
            ls[q] = f2bf(xx - bf2f(h));
        }
        *(uint4*)&nv[NV_OFS(0, kg, slot) * 8] = *(const uint4*)hs;
        *(uint4*)&nv[NV_OFS(1, kg, slot) * 8] = *(const uint4*)ls;
    }
}

// ---------------- kernel 2: MFMA pairwise exp-sim, column sums only ----------
// Full matrix (R8: triangle's shuffle epilogue costs more than halved compute
// saves). 64x64 tile/block, 4 waves = four 32x32 MFMA quadrants; fp32 sim via
// bf16 hi/lo split (hi*hi + hi*lo + lo*hi).
// Staging via global_load_lds width=16 from the fragment-major layout:
// (side,plane,chunk) wave-uniform, row=lane -> dest = uniform base + lane*16.
// NO device-scope fences (R5: per-block fence = per-block L2 writeback on
// non-coherent XCD L2s, 270us). Kernel boundary provides coherence once.
#define EXP2_SCALE 20.609929155556605f   // 1/(0.07*ln2): exp(s/T)=exp2(s*this)

__global__ __launch_bounds__(256, 4) void pair_kernel(
        const unsigned short* __restrict__ nv,
        const int* __restrict__ lab_sel,
        const int* __restrict__ nsel_g,
        float* __restrict__ pos,
        float* __restrict__ neg) {
    const int nsel = *nsel_g;
    const int it = blockIdx.y, jt = blockIdx.x;
    const int i0 = it * 64, j0 = jt * 64;
    if (i0 >= nsel || j0 >= nsel) return;

    // [side A/B][plane hi/lo][chunk 0..7][row 0..63][8 bf16] = 32 KB
    __shared__ __align__(16) unsigned short frags[2][2][8][64][8];
    __shared__ int La[64], Lb[64];

    const int t = threadIdx.x;
    const int wave = t >> 6, lane = t & 63;

    // stage 32 x 1KiB segments: combo = it8*4 + wave -> (side,plane,chunk)
    #pragma unroll
    for (int it8 = 0; it8 < 8; ++it8) {
        const int combo = it8 * 4 + wave;
        const int side  = combo >> 4;
        const int plane = (combo >> 3) & 1;
        const int c     = combo & 7;
        const int base0 = (side ? j0 : i0);
        async_copy16(&nv[NV_OFS(plane, c, base0 + lane) * 8],
                     &frags[side][plane][c][lane][0]);
    }
    if (t < 64)       La[t]      = lab_sel[i0 + t];      // junk past nsel masked later
    else if (t < 128) Lb[t - 64] = lab_sel[j0 + t - 64];
    __syncthreads();   // drains vmcnt (incl. global_load_lds) before LDS reads

    const int qi = (wave >> 1) * 32, qj = (wave & 1) * 32;
    const int half = lane >> 5, l31 = lane & 31;
    const int ra = qi + l31, rb = qj + l31;

    f32x16 acc;
    #pragma unroll
    for (int r = 0; r < 16; ++r) acc[r] = 0.0f;

    #pragma unroll
    for (int s = 0; s < 4; ++s) {
        const int c = 2 * s + half;
        const short8v ah = *(const short8v*)&frags[0][0][c][ra][0];
        const short8v al = *(const short8v*)&frags[0][1][c][ra][0];
        const short8v bh = *(const short8v*)&frags[1][0][c][rb][0];
        const short8v bl = *(const short8v*)&frags[1][1][c][rb][0];
        acc = __builtin_amdgcn_mfma_f32_32x32x16_bf16(ah, bh, acc, 0, 0, 0);
        acc = __builtin_amdgcn_mfma_f32_32x32x16_bf16(ah, bl, acc, 0, 0, 0);
        acc = __builtin_amdgcn_mfma_f32_32x32x16_bf16(al, bh, acc, 0, 0, 0);
    }

    // epilogue: C/D layout col=lane&31, row=(reg&3)+8*(reg>>2)+4*(lane>>5)
    const int colL = qj + l31;
    const int jg = j0 + colL;
    const int Lj = Lb[colL];
    float cp = 0.0f, cn = 0.0f;
    #pragma unroll
    for (int r = 0; r < 16; ++r) {
        const int rowL = qi + (r & 3) + 8 * (r >> 2) + 4 * half;
        const int ig = i0 + rowL;
        const bool valid = (ig < nsel) && (jg < nsel) && (ig != jg);
        const float d = valid ? exp2f(acc[r] * EXP2_SCALE) : 0.0f;
        if (La[rowL] == Lj) cp += d; else cn += d;
    }
    // combine the two lane-halves (rows split across halves), then scatter cols
    cp += __shfl_xor(cp, 32, 64);
    cn += __shfl_xor(cn, 32, 64);
    if (half == 0 && jg < nsel) {
        atomicAdd(&pos[jg], cp);
        atomicAdd(&neg[jg], cn);
    }
}

// ---------------- kernel 3: final loss reduction -----------------------------
__global__ void loss_kernel(const float* __restrict__ pos,
                            const float* __restrict__ neg,
                            const int* __restrict__ nsel_g,
                            float* __restrict__ out) {
    const int nsel = *nsel_g;
    float s = 0.0f;
    for (int i = threadIdx.x; i < nsel; i += 256) {
        const float fr = pos[i] / (pos[i] + neg[i]);
        s += -logf(fr);
    }
    __shared__ float red[256];
    red[threadIdx.x] = s;
    __syncthreads();
    for (int off = 128; off > 0; off >>= 1) {
        if (threadIdx.x < off) red[threadIdx.x] += red[threadIdx.x + off];
        __syncthreads();
    }
    if (threadIdx.x == 0) out[0] = red[0] / (float)(nsel > 0 ? nsel : 1);
}

// ---------------- launch -----------------------------------------------------
extern "C" void kernel_launch(void* const* d_in, const int* in_sizes, int n_in,
                              void* d_out, int out_size, void* d_ws, size_t ws_size,
                              hipStream_t stream) {
    const float* features = (const float*)d_in[0];
    const int*   labels   = (const int*)d_in[1];
    float*       out      = (float*)d_out;
    char*        ws       = (char*)d_ws;

    int*   nsel_g   = (int*)(ws);
    int*   lab_sel  = (int*)(ws + 1024);                      // 4096 ints
    float* pos      = (float*)(ws + 1024 + 16384);            // 4096 fp32
    float* neg      = pos + NSEL_CAP;
    unsigned short* nv = (unsigned short*)(ws + 1024 + 16384 + 32768);  // 1 MiB

    select_norm_kernel<<<128, 256, 0, stream>>>(features, labels, nsel_g, lab_sel,
                                                nv, pos, neg);
    pair_kernel<<<dim3(NT, NT), 256, 0, stream>>>(nv, lab_sel, nsel_g, pos, neg);
    loss_kernel<<<1, 256, 0, stream>>>(pos, neg, nsel_g, out);
}

// Round 12
// 82.641 us; speedup vs baseline: 1.0473x; 1.0473x over previous
//
#include <hip/hip_runtime.h>
#include <hip/hip_bf16.h>

// Problem-fixed shapes: features [4,64,2048] fp32 (feats[m][c] = flat[c*8192+m]),
// labels [8192] int32, NUM_CLASSES=4, TEMP=0.07, scalar fp32 out.
#define M_TOT 8192
#define NCLS 4
#define NSEL_CAP 4096   // nsel ~ 3000 (deterministic for this fixed input); 4096 guard
#define NT 64           // 64x64 tile grid covers NSEL_CAP

typedef __attribute__((ext_vector_type(8)))  short short8v;  // 8 bf16 = 4 VGPRs
typedef __attribute__((ext_vector_type(16))) float f32x16;   // MFMA 32x32 acc

// async 16B global->LDS copy (device pass only: host pass must not see the
// builtin, its pointer params fail host typechecking)
__device__ __forceinline__ void async_copy16(const void* gsrc, void* ldst) {
#if defined(__HIP_DEVICE_COMPILE__)
    __builtin_amdgcn_global_load_lds(
        (const __attribute__((address_space(1))) void*)gsrc,
        (__attribute__((address_space(3))) void*)ldst, 16, 0, 0);
#endif
}

// ---------------- JAX threefry-2x32, key = PRNGKey(42) = (0, 42) -------------
// Counter pair (j, j+4096); JAX output: bits[m] = x0 if m<4096 else x1.
__device__ __forceinline__ unsigned int rotl32(unsigned int x, unsigned int r) {
    return (x << r) | (x >> (32u - r));
}

__device__ __forceinline__ uint2 threefry_pair_key42(unsigned int j) {
    const unsigned int ks0 = 0u;
    const unsigned int ks1 = 42u;
    const unsigned int ks2 = 0x1BD11BDAu ^ 0u ^ 42u;
    unsigned int x0 = j + ks0;
    unsigned int x1 = (j + 4096u) + ks1;
#define TF_RND(r) { x0 += x1; x1 = rotl32(x1, (r)); x1 ^= x0; }
    TF_RND(13u) TF_RND(15u) TF_RND(26u) TF_RND(6u)
    x0 += ks1; x1 += ks2 + 1u;
    TF_RND(17u) TF_RND(29u) TF_RND(16u) TF_RND(24u)
    x0 += ks2; x1 += ks0 + 2u;
    TF_RND(13u) TF_RND(15u) TF_RND(26u) TF_RND(6u)
    x0 += ks0; x1 += ks1 + 3u;
    TF_RND(17u) TF_RND(29u) TF_RND(16u) TF_RND(24u)
    x0 += ks1; x1 += ks2 + 4u;
    TF_RND(13u) TF_RND(15u) TF_RND(26u) TF_RND(6u)
    x0 += ks2; x1 += ks0 + 5u;
#undef TF_RND
    return make_uint2(x0, x1);
}

// JAX uniform from bits: bitcast((bits>>9)|0x3F800000) - 1.0; select iff u < p.
__device__ __forceinline__ float bits_to_unit(unsigned int bits) {
    return __uint_as_float((bits >> 9) | 0x3F800000u) - 1.0f;
}

// bf16 round-to-nearest-even helpers
__device__ __forceinline__ unsigned short f2bf(float x) {
    const unsigned int u = __float_as_uint(x);
    return (unsigned short)((u + 0x7FFFu + ((u >> 16) & 1u)) >> 16);
}
__device__ __forceinline__ float bf2f(unsigned short b) {
    return __uint_as_float(((unsigned int)b) << 16);
}

// Global nv layout is FRAGMENT-MAJOR, identical to pair's LDS layout:
//   nv[plane(hi=0,lo=1)][chunk c 0..7][point 0..4095][8 bf16]
// so pair staging is a contiguous 1KiB copy per (plane,chunk,64-point row)
// and can use global_load_lds (wave-uniform LDS base + lane*16).
#define NV_OFS(plane, c, p) (((((plane) << 3) + (c)) << 12) + (p))

// ---------------- kernel 1: fused select + normalize -------------------------
// 128 blocks x 256. Every block redundantly computes the full selection
// (deterministic pure function of labels + threefry), compacts into LDS, then
// normalizes ITS OWN 32 slots (8 threads/point). Feature reads are a strided
// gather, but features (2 MiB) is fully L2/L3-resident so amplification hits
// cache, not HBM — R11 measured that LDS-staging "coalescing" costs +4us net.
__global__ __launch_bounds__(256) void select_norm_kernel(
        const float* __restrict__ features,
        const int* __restrict__ labels,
        int* __restrict__ nsel_g,
        int* __restrict__ lab_sel,
        unsigned short* __restrict__ nv,     // [2][8][4096][8] bf16
        float* __restrict__ pos,
        float* __restrict__ neg) {
    __shared__ int   hist[NCLS];
    __shared__ float keepp[NCLS];
    __shared__ int   wtot[4];
    __shared__ int   lds_m[NSEL_CAP];    // 16 KB selected-point list
    const int t = threadIdx.x, b = blockIdx.x;
    const int lane = t & 63, w = t >> 6;

    const int gid = b * 256 + t;
    if (gid < NSEL_CAP) { pos[gid] = 0.0f; neg[gid] = 0.0f; }
    if (t < NCLS) hist[t] = 0;
    __syncthreads();

    // full histogram (redundant per block; L2-cached labels)
    {
        const int m0 = t * 32;
        int c0 = 0, c1 = 0, c2 = 0, c3 = 0;
        for (int r = 0; r < 32; ++r) {
            const int lab = labels[m0 + r];
            c0 += (lab == 0); c1 += (lab == 1); c2 += (lab == 2); c3 += (lab == 3);
        }
        int cc[4] = {c0, c1, c2, c3};
        #pragma unroll
        for (int cls = 0; cls < NCLS; ++cls) {
            int v = cc[cls];
            for (int off = 32; off > 0; off >>= 1) v += __shfl_down(v, off, 64);
            if (lane == 0) atomicAdd(&hist[cls], v);
        }
    }
    __syncthreads();
    if (t < NCLS) keepp[t] = fminf(750.0f / ((float)hist[t] + 1.0f), 1.0f);
    __syncthreads();

    // selection: thread t owns counter-lanes j = t*16..t*16+15, each yielding
    // m=j (x0) and m=j+4096 (x1).
    const int jb = t * 16;
    unsigned int flags = 0u;
    int cnt = 0;
    for (int r = 0; r < 16; ++r) {
        const uint2 bb = threefry_pair_key42((unsigned int)(jb + r));
        if (bits_to_unit(bb.x) < keepp[labels[jb + r]])        { flags |= 1u << r;        ++cnt; }
        if (bits_to_unit(bb.y) < keepp[labels[jb + r + 4096]]) { flags |= 1u << (16 + r); ++cnt; }
    }
    // wave-inclusive scan -> block-wide exclusive base
    int x = cnt;
    #pragma unroll
    for (int off = 1; off < 64; off <<= 1) {
        const int y = __shfl_up(x, off, 64);
        if (lane >= off) x += y;
    }
    if (lane == 63) wtot[w] = x;
    const int excl = x - cnt;
    __syncthreads();
    int base = excl;
    for (int w2 = 0; w2 < w; ++w2) base += wtot[w2];
    const int nsel = wtot[0] + wtot[1] + wtot[2] + wtot[3];
    if (b == 0 && t == 0) *nsel_g = nsel;
    for (int r = 0; r < 16; ++r) {
        if (flags & (1u << r))        lds_m[base++] = jb + r;
        if (flags & (1u << (16 + r))) lds_m[base++] = jb + r + 4096;
    }
    __syncthreads();

    // normalize this block's 32 slots, 8 threads/point; kg = chunk index
    const int p  = b * 32 + (t >> 3);
    const int kg = t & 7;
    if (p >= nsel) return;
    const int m = lds_m[p];
    if (kg == 0) lab_sel[p] = labels[m];
    float v[8];
    float ss = 0.0f;
    #pragma unroll
    for (int q = 0; q < 8; ++q) {
        v[q] = features[(kg * 8 + q) * M_TOT + m];
        ss += v[q] * v[q];
    }
    ss += __shfl_xor(ss, 1, 8);
    ss += __shfl_xor(ss, 2, 8);
    ss += __shfl_xor(ss, 4, 8);
    const float rn = rsqrtf(ss);
    unsigned short hs[8], ls[8];
    #pragma unroll
    for (int q = 0; q < 8; ++q) {
        const float xx = v[q] * rn;
        const unsigned short h = f2bf(xx);
        hs[q] = h;
        ls[q] = f2bf(xx - bf2f(h));
    }
    *(uint4*)&nv[NV_OFS(0, kg, p) * 8] = *(const uint4*)hs;
    *(uint4*)&nv[NV_OFS(1, kg, p) * 8] = *(const uint4*)ls;
}

// ---------------- kernel 2: MFMA pairwise exp-sim, column sums only ----------
// Full matrix (R8 showed triangle's shuffle epilogue costs more than the
// halved compute saves). 64x64 tile/block, 4 waves = four 32x32 MFMA
// quadrants; fp32 sim via bf16 hi/lo split (hi*hi + hi*lo + lo*hi).
// Staging via global_load_lds width=16: per (iter,wave) the (side,plane,chunk)
// is uniform, row=lane -> LDS dest = uniform base + lane*16 (the HW rule),
// and the fragment-major global layout makes the read a contiguous 1KiB/wave.
// NO device-scope fences (R5: per-block fence = per-block L2 writeback on
// non-coherent XCD L2s, 270us). Kernel boundary provides coherence once.
#define EXP2_SCALE 20.609929155556605f   // 1/(0.07*ln2): exp(s/T)=exp2(s*this)

__global__ __launch_bounds__(256, 4) void pair_kernel(
        const unsigned short* __restrict__ nv,
        const int* __restrict__ lab_sel,
        const int* __restrict__ nsel_g,
        float* __restrict__ pos,
        float* __restrict__ neg) {
    const int nsel = *nsel_g;
    const int it = blockIdx.y, jt = blockIdx.x;
    const int i0 = it * 64, j0 = jt * 64;
    if (i0 >= nsel || j0 >= nsel) return;

    // [side A/B][plane hi/lo][chunk 0..7][row 0..63][8 bf16] = 32 KB
    __shared__ __align__(16) unsigned short frags[2][2][8][64][8];
    __shared__ int La[64], Lb[64];

    const int t = threadIdx.x;
    const int wave = t >> 6, lane = t & 63;

    // stage 32 x 1KiB segments: combo = it8*4 + wave -> (side,plane,chunk)
    // LDS dest = wave-uniform base + lane*16 (the global_load_lds HW rule).
    #pragma unroll
    for (int it8 = 0; it8 < 8; ++it8) {
        const int combo = it8 * 4 + wave;
        const int side  = combo >> 4;
        const int plane = (combo >> 3) & 1;
        const int c     = combo & 7;
        const int base0 = (side ? j0 : i0);
        async_copy16(&nv[NV_OFS(plane, c, base0 + lane) * 8],
                     &frags[side][plane][c][lane][0]);
    }
    if (t < 64)       La[t]      = lab_sel[i0 + t];      // junk past nsel masked later
    else if (t < 128) Lb[t - 64] = lab_sel[j0 + t - 64];
    __syncthreads();   // drains vmcnt (incl. global_load_lds) before LDS reads

    const int qi = (wave >> 1) * 32, qj = (wave & 1) * 32;
    const int half = lane >> 5, l31 = lane & 31;
    const int ra = qi + l31, rb = qj + l31;

    f32x16 acc;
    #pragma unroll
    for (int r = 0; r < 16; ++r) acc[r] = 0.0f;

    #pragma unroll
    for (int s = 0; s < 4; ++s) {
        const int c = 2 * s + half;
        const short8v ah = *(const short8v*)&frags[0][0][c][ra][0];
        const short8v al = *(const short8v*)&frags[0][1][c][ra][0];
        const short8v bh = *(const short8v*)&frags[1][0][c][rb][0];
        const short8v bl = *(const short8v*)&frags[1][1][c][rb][0];
        acc = __builtin_amdgcn_mfma_f32_32x32x16_bf16(ah, bh, acc, 0, 0, 0);
        acc = __builtin_amdgcn_mfma_f32_32x32x16_bf16(ah, bl, acc, 0, 0, 0);
        acc = __builtin_amdgcn_mfma_f32_32x32x16_bf16(al, bh, acc, 0, 0, 0);
    }

    // epilogue: C/D layout col=lane&31, row=(reg&3)+8*(reg>>2)+4*(lane>>5)
    const int colL = qj + l31;
    const int jg = j0 + colL;
    const int Lj = Lb[colL];
    float cp = 0.0f, cn = 0.0f;
    #pragma unroll
    for (int r = 0; r < 16; ++r) {
        const int rowL = qi + (r & 3) + 8 * (r >> 2) + 4 * half;
        const int ig = i0 + rowL;
        const bool valid = (ig < nsel) && (jg < nsel) && (ig != jg);
        const float d = valid ? exp2f(acc[r] * EXP2_SCALE) : 0.0f;
        if (La[rowL] == Lj) cp += d; else cn += d;
    }
    // combine the two lane-halves (rows split across halves), then scatter cols
    cp += __shfl_xor(cp, 32, 64);
    cn += __shfl_xor(cn, 32, 64);
    if (half == 0 && jg < nsel) {
        atomicAdd(&pos[jg], cp);
        atomicAdd(&neg[jg], cn);
    }
}

// ---------------- kernel 3: final loss reduction -----------------------------
__global__ void loss_kernel(const float* __restrict__ pos,
                            const float* __restrict__ neg,
                            const int* __restrict__ nsel_g,
                            float* __restrict__ out) {
    const int nsel = *nsel_g;
    float s = 0.0f;
    for (int i = threadIdx.x; i < nsel; i += 256) {
        const float fr = pos[i] / (pos[i] + neg[i]);
        s += -logf(fr);
    }
    __shared__ float red[256];
    red[threadIdx.x] = s;
    __syncthreads();
    for (int off = 128; off > 0; off >>= 1) {
        if (threadIdx.x < off) red[threadIdx.x] += red[threadIdx.x + off];
        __syncthreads();
    }
    if (threadIdx.x == 0) out[0] = red[0] / (float)(nsel > 0 ? nsel : 1);
}

// ---------------- launch -----------------------------------------------------
extern "C" void kernel_launch(void* const* d_in, const int* in_sizes, int n_in,
                              void* d_out, int out_size, void* d_ws, size_t ws_size,
                              hipStream_t stream) {
    const float* features = (const float*)d_in[0];
    const int*   labels   = (const int*)d_in[1];
    float*       out      = (float*)d_out;
    char*        ws       = (char*)d_ws;

    int*   nsel_g   = (int*)(ws);
    int*   lab_sel  = (int*)(ws + 1024);                      // 4096 ints
    float* pos      = (float*)(ws + 1024 + 16384);            // 4096 fp32
    float* neg      = pos + NSEL_CAP;
    unsigned short* nv = (unsigned short*)(ws + 1024 + 16384 + 32768);  // 1 MiB

    select_norm_kernel<<<128, 256, 0, stream>>>(features, labels, nsel_g, lab_sel,
                                                nv, pos, neg);
    pair_kernel<<<dim3(NT, NT), 256, 0, stream>>>(nv, lab_sel, nsel_g, pos, neg);
    loss_kernel<<<1, 256, 0, stream>>>(pos, neg, nsel_g, out);
}